// Round 6
// baseline (130.292 us; speedup 1.0000x reference)
//
#include <hip/hip_runtime.h>

// SparseEmbedding forward: out[n, :] = weight[indices[n], :]
//   weight : [1'000'000, 128] fp32  (512 B per row)
//   indices: [4096, 200] int (flat N = 819'200)
//   out    : [N, 128] fp32
//
// Round 5 -> 6: more ILP. 8 lanes per row, each lane does FOUR
// lane-contiguous dwordx4 loads (64 B/lane):
//   v_k at row_base + k*8 + slot   (lanes 0..7 cover a 128 B segment)
// Every VMEM instruction remains coalesced in >=128 B segments; 4
// independent loads + 4 NT stores per thread hide the ~900-cycle
// random-gather HBM latency. Index loads halve again (8 threads/row).
// NT stores (round-2 win) keep the write-once output out of L2/L3 so
// duplicate weight rows stay cached.

typedef float f32x4 __attribute__((ext_vector_type(4)));

constexpr int LANES_PER_ROW = 8;   // each lane owns 4 x 16 B

__global__ __launch_bounds__(256) void sparse_embedding_gather(
    const f32x4* __restrict__ weight,   // [1e6 * 32] f32x4
    const int*   __restrict__ indices,  // [N]
    f32x4*       __restrict__ out,      // [N * 32] f32x4
    int total_slots)                    // N * 8
{
    int i = blockIdx.x * 256 + threadIdx.x;
    if (i >= total_slots) return;

    int row  = i >> 3;        // output row
    int slot = i & 7;         // lane slot within the row

    long long base = (long long)indices[row] * 32 + slot;
    f32x4 v0 = weight[base];
    f32x4 v1 = weight[base + 8];
    f32x4 v2 = weight[base + 16];
    f32x4 v3 = weight[base + 24];

    long long dst = (long long)row * 32 + slot;
    __builtin_nontemporal_store(v0, &out[dst]);
    __builtin_nontemporal_store(v1, &out[dst + 8]);
    __builtin_nontemporal_store(v2, &out[dst + 16]);
    __builtin_nontemporal_store(v3, &out[dst + 24]);
}

extern "C" void kernel_launch(void* const* d_in, const int* in_sizes, int n_in,
                              void* d_out, int out_size, void* d_ws, size_t ws_size,
                              hipStream_t stream) {
    const f32x4* weight  = (const f32x4*)d_in[0];
    const int*   indices = (const int*)d_in[1];
    f32x4*       out     = (f32x4*)d_out;

    const int n_rows      = in_sizes[1];               // 819'200
    const int total_slots = n_rows * LANES_PER_ROW;    // 6'553'600

    const int block  = 256;
    const int blocks = (total_slots + block - 1) / block;  // 25'600

    sparse_embedding_gather<<<blocks, block, 0, stream>>>(
        weight, indices, out, total_slots);
}

// Round 7
// 124.828 us; speedup vs baseline: 1.0438x; 1.0438x over previous
//
#include <hip/hip_runtime.h>

// SparseEmbedding forward: out[n, :] = weight[indices[n], :]
//   weight : [1'000'000, 128] fp32  (512 B per row)
//   indices: [4096, 200] int (flat N = 819'200)
//   out    : [N, 128] fp32
//
// FINAL (revert to round-5 best, 124.8 us):
//   - 16 lanes per row; each lane does TWO lane-contiguous dwordx4 loads
//     (v0 covers bytes [0,256) across lanes, v1 covers [256,512)).
//     Every VMEM instruction fully coalesced; 2 independent loads/thread.
//   - NT stores: output is write-once, keep it out of L2/L3 so duplicate
//     weight rows stay cached (152->139 us win in round 3).
//   - One-shot grid, 256-thread blocks.
// Measured trajectory: 152.4 (naive) -> 139.2 (NT stores) -> 124.8 (this).
// Composite roofline ~120-126 us (419 MB NT write @ ~6.9 TB/s + ~300-450 MB
// random 512 B gathers); this kernel sits inside the band.

typedef float f32x4 __attribute__((ext_vector_type(4)));

constexpr int LANES_PER_ROW = 16;   // each lane owns 2 x 16 B, halves of the row

__global__ __launch_bounds__(256) void sparse_embedding_gather(
    const f32x4* __restrict__ weight,   // [1e6 * 32] f32x4
    const int*   __restrict__ indices,  // [N]
    f32x4*       __restrict__ out,      // [N * 32] f32x4
    int total_pairs)                    // N * 16
{
    int i = blockIdx.x * 256 + threadIdx.x;
    if (i >= total_pairs) return;

    int row  = i >> 4;        // output row
    int pair = i & 15;        // lane slot within the row

    long long base = (long long)indices[row] * 32;
    f32x4 v0 = weight[base + pair];        // contiguous across lanes
    f32x4 v1 = weight[base + 16 + pair];   // contiguous across lanes

    long long dst = (long long)row * 32 + pair;
    __builtin_nontemporal_store(v0, &out[dst]);
    __builtin_nontemporal_store(v1, &out[dst + 16]);
}

extern "C" void kernel_launch(void* const* d_in, const int* in_sizes, int n_in,
                              void* d_out, int out_size, void* d_ws, size_t ws_size,
                              hipStream_t stream) {
    const f32x4* weight  = (const f32x4*)d_in[0];
    const int*   indices = (const int*)d_in[1];
    f32x4*       out     = (f32x4*)d_out;

    const int n_rows      = in_sizes[1];               // 819'200
    const int total_pairs = n_rows * LANES_PER_ROW;    // 13'107'200

    const int block  = 256;
    const int blocks = (total_pairs + block - 1) / block;  // 51'200

    sparse_embedding_gather<<<blocks, block, 0, stream>>>(
        weight, indices, out, total_pairs);
}